// Round 17
// baseline (106.036 us; speedup 1.0000x reference)
//
#include <hip/hip_runtime.h>
#include <stdint.h>

// B=32, La=512, Lq=64, H=1024. Plain-fp16 pipeline (absmax 0.0078 vs thr 0.0456).
// R16 structure; prep slimmed to 3 transposes (W12T/W21T/W22T). Row-major fp32
// operands (Q, W11) are converted inline during GEMM staging (proven g2 pattern);
// k-major operands stay prep'd fp16 + global_load_lds (R14 lesson).
// prep_W3: W12T, W21T, W22T
// g1: Pcat = Q@[W11;W12^T]^T (128x64, remap) || P3T = (Q@W21)^T (128x64), BK=128
// g2: scores = A@Pcat^T, 32x128 full-K BK=128; fused aq row-softmax; qa -> Spar fp32
// softmax_cols: qa = colsoftmax(Spar) fp16
// g3: PmaxA = colmax(relu(aq@P3T^T)) LDS-free (K=64) || ctx = qa@A (BK=64)
// g4: PmaxQ = colmax64(relu(ctx@W22T^T)) + fused final combine, BK=128

using f16x8 = __attribute__((ext_vector_type(8))) _Float16;
using f32x4 = __attribute__((ext_vector_type(4))) float;
typedef const __attribute__((address_space(1))) void* gas_t;
typedef __attribute__((address_space(3))) void* las_t;

__device__ __forceinline__ unsigned short f2h(float x) {
  _Float16 h = (_Float16)x;
  return __builtin_bit_cast(unsigned short, h);
}

// ---------------- prep: 3 transposed fp16 weight copies ----------------

__global__ __launch_bounds__(256) void prep_W3(
    const float* __restrict__ W12, const float* __restrict__ W21,
    const float* __restrict__ W22,
    unsigned short* __restrict__ W12T, unsigned short* __restrict__ W21T,
    unsigned short* __restrict__ W22T)
{
  __shared__ float tile[32][33];
  int z = blockIdx.z;
  const float* src = z == 0 ? W12 : z == 1 ? W21 : W22;
  unsigned short* dst = z == 0 ? W12T : z == 1 ? W21T : W22T;
  int r0 = blockIdx.y * 32, c0 = blockIdx.x * 32;
  int tx = threadIdx.x, ty = threadIdx.y;
  #pragma unroll
  for (int i = 0; i < 4; ++i)
    tile[ty + i * 8][tx] = src[(long)(r0 + ty + i * 8) * 1024 + c0 + tx];
  __syncthreads();
  #pragma unroll
  for (int i = 0; i < 4; ++i) {
    float v = tile[tx][ty + i * 8];
    dst[(long)(c0 + ty + i * 8) * 1024 + r0 + tx] = f2h(v);
  }
}

// ---------------- generic MFMA GEMM body (C = A @ B^T), NC x 32-k chunks, fp16 ----------------
// ASRC: 0 = fp16 gload_lds, 1 = fp32 row-major reg-staged.
// BSRC: 0 = fp16 gload_lds, 1 = fp32 row-major reg-staged, 2 = fp32 k-major reg-staged.
// OUT: 1=Pcat remap, 2=fp16 batched, 3=transpose remap, 6=relu+colmax64+final (Bf=PmaxA).
template<int BM, int BN, int OUT, int ASRC, int BSRC, int NC>
__device__ __forceinline__ void gemm_body(
    char* smem, int bx, int by, int z,
    const unsigned short* __restrict__ Ah, const float* __restrict__ Af,
    const unsigned short* __restrict__ Bh, const float* __restrict__ Bf,
    float* __restrict__ Cf, unsigned short* __restrict__ Ch,
    int M, int N, int K, int ldA, int ldB, int ldC, long sA, long sB, long sC, int n0B)
{
  constexpr int ACH = BM * 64, BCH = BN * 64;  // bytes per 32-k chunk
  constexpr int MI = BM / 32, NI = BN / 32;
  char* As = smem;
  char* Bs = smem + NC * ACH;

  const int m0 = by * BM, n0 = bx * BN;
  const int t = threadIdx.x, lane = t & 63;
  const int wid = t >> 6, wr = wid >> 1, wc = wid & 1;

  const unsigned short* Ab16 = (ASRC == 0) ? Ah + (long)z * sA : nullptr;
  const float*          Abf  = (ASRC == 1) ? Af + (long)z * sA : nullptr;
  const unsigned short* Bb16 = (BSRC == 0) ? Bh + (long)z * sB : nullptr;
  const float*          Bbf  = (BSRC != 0) ? Bf + (long)z * sB : nullptr;

  f32x4 acc[MI][NI];
  #pragma unroll
  for (int i = 0; i < MI; ++i)
    #pragma unroll
    for (int j = 0; j < NI; ++j)
      acc[i][j] = f32x4{0.f, 0.f, 0.f, 0.f};

  auto stage4k = [&](char* lbuf, const unsigned short* g, int ld, int row0, int k0, int rmax) {
    int ob = t * 16;
    int e  = ob ^ (((ob >> 7) & 3) << 4);
    int m  = e >> 6, k = (e & 63) >> 1;
    int row = row0 + m; row = row < rmax ? row : rmax - 1;
    const unsigned short* gp = g + (long)row * ld + k0 + k;
    char* lp = lbuf + (t & ~63) * 16;  // wave-uniform; HW adds lane*16
    __builtin_amdgcn_global_load_lds((gas_t)(const void*)gp, (las_t)(void*)lp, 16, 0, 0);
  };
  // fp32 row-major: 8 consecutive fp32 of row (row0+m), convert, 16B ds_write (linear LDS,
  // inverse-swizzled logical index — same convention as stage4k)
  auto stageRowF32 = [&](char* lbuf, const float* g, int ld, int row0, int k0) {
    int ob = t * 16;
    int e  = ob ^ (((ob >> 7) & 3) << 4);
    int m  = e >> 6, ke = (e & 63) >> 1;
    const float* src = g + (long)(row0 + m) * ld + k0 + ke;
    float4 v0 = *(const float4*)src;
    float4 v1 = *(const float4*)(src + 4);
    f16x8 pk;
    pk[0] = (_Float16)v0.x; pk[1] = (_Float16)v0.y; pk[2] = (_Float16)v0.z; pk[3] = (_Float16)v0.w;
    pk[4] = (_Float16)v1.x; pk[5] = (_Float16)v1.y; pk[6] = (_Float16)v1.z; pk[7] = (_Float16)v1.w;
    *(f16x8*)(lbuf + ob) = pk;
  };
  // fp32 k-major (B[n][k] = g[k][n]): coalesced-across-lanes per k-row
  auto stageKF32 = [&](char* lbuf, const float* g, int ld, int nb, int k0) {
    int ob = t * 16;
    int e  = ob ^ (((ob >> 7) & 3) << 4);
    int n  = e >> 6, kb = (e & 63) >> 1;
    f16x8 pk;
    #pragma unroll
    for (int j = 0; j < 8; ++j)
      pk[j] = (_Float16)g[(long)(k0 + kb + j) * ld + nb + n];
    *(f16x8*)(lbuf + ob) = pk;
  };
  auto ldfrag = [&](const char* lbuf, int rr) -> f16x8 {
    int ob = rr * 64 + (lane >> 4) * 16;
    ob ^= ((ob >> 7) & 3) << 4;
    return *(const f16x8*)(lbuf + ob);
  };
  auto compute32 = [&](const char* Ac, const char* Bc) {
    f16x8 ah[MI];
    #pragma unroll
    for (int mi = 0; mi < MI; ++mi)
      ah[mi] = ldfrag(Ac, wr * (BM / 2) + mi * 16 + (lane & 15));
    #pragma unroll
    for (int ni = 0; ni < NI; ++ni) {
      f16x8 bh = ldfrag(Bc, wc * (BN / 2) + ni * 16 + (lane & 15));
      #pragma unroll
      for (int mi = 0; mi < MI; ++mi)
        acc[mi][ni] = __builtin_amdgcn_mfma_f32_16x16x32_f16(ah[mi], bh, acc[mi][ni], 0, 0, 0);
    }
  };

  for (int k0 = 0; k0 < K; k0 += 32 * NC) {
    #pragma unroll
    for (int c = 0; c < NC; ++c) {
      int kc = k0 + 32 * c;
      char* Ac = As + c * ACH;
      if (ASRC == 0) {
        stage4k(Ac, Ab16, ldA, m0, kc, M);
        if (BM == 128) stage4k(Ac + 4096, Ab16, ldA, m0 + 64, kc, M);
      } else {
        stageRowF32(Ac, Abf, ldA, m0, kc);
        if (BM == 128) stageRowF32(Ac + 4096, Abf, ldA, m0 + 64, kc);
      }
    }
    #pragma unroll
    for (int c = 0; c < NC; ++c) {
      int kc = k0 + 32 * c;
      char* Bc = Bs + c * BCH;
      if (BSRC == 0)      stage4k(Bc, Bb16, ldB, n0B, kc, N);
      else if (BSRC == 1) stageRowF32(Bc, Bbf, ldB, n0B, kc);
      else                stageKF32(Bc, Bbf, ldB, n0B, kc);
    }
    __syncthreads();
    #pragma unroll
    for (int c = 0; c < NC; ++c) compute32(As + c * ACH, Bs + c * BCH);
    __syncthreads();
  }

  if (OUT == 6) {
    float* red = (float*)smem;  // safe: k-loop ended with __syncthreads
    #pragma unroll
    for (int ni = 0; ni < NI; ++ni) {
      float pm = 0.0f;  // relu floor
      #pragma unroll
      for (int mi = 0; mi < MI; ++mi)
        #pragma unroll
        for (int r = 0; r < 4; ++r)
          pm = fmaxf(pm, acc[mi][ni][r]);
      int g = wr * 4 + (lane >> 4);
      int col = wc * (BN / 2) + ni * 16 + (lane & 15);
      red[g * BN + col] = pm;
    }
    __syncthreads();
    if (t < BN) {  // BM=BN=64, by = batch; Bf = PmaxA [128][1024]; Cf = out
      float pq = red[t];
      #pragma unroll
      for (int g = 1; g < 8; ++g) pq = fmaxf(pq, red[g * BN + t]);
      float pa = Bf[(long)(by * 4) * 1024 + n0 + t];
      #pragma unroll
      for (int mt = 1; mt < 4; ++mt)
        pa = fmaxf(pa, Bf[(long)(by * 4 + mt) * 1024 + n0 + t]);
      Cf[(long)by * 1024 + n0 + t] = 0.5f * pa + 0.5f * pq;
    }
    return;
  }

  // OUT 1/2/3: stage C-tile to LDS fp16, then coalesced 16B stores.
  unsigned short* ct = (unsigned short*)smem;  // [BM][BN] (OUT 1/2) or [BN][BM] (OUT 3)
  #pragma unroll
  for (int mi = 0; mi < MI; ++mi)
    #pragma unroll
    for (int r = 0; r < 4; ++r) {
      int ml = wr * (BM / 2) + mi * 16 + (lane >> 4) * 4 + r;
      #pragma unroll
      for (int ni = 0; ni < NI; ++ni) {
        int nl = wc * (BN / 2) + ni * 16 + (lane & 15);
        unsigned short hv = f2h(acc[mi][ni][r]);
        if (OUT == 3) ct[nl * BM + ml] = hv;
        else          ct[ml * BN + nl] = hv;
      }
    }
  __syncthreads();

  if (OUT == 1) {
    constexpr int ITER = BM * (BN / 8) / 256;
    #pragma unroll
    for (int i = 0; i < ITER; ++i) {
      int c = i * 256 + t;
      int ml = c / (BN / 8), cc = (c % (BN / 8)) * 8;
      int gm = m0 + ml;
      int b = gm >> 6, q = gm & 63;
      long dst = (long)b * 131072 + (long)((n0 >> 10) * 64 + q) * 1024 + (n0 & 1023) + cc;
      *(f16x8*)(Ch + dst) = *(const f16x8*)(ct + ml * BN + cc);
    }
  } else if (OUT == 3) {
    constexpr int ITER = BN * (BM / 8) / 256;
    #pragma unroll
    for (int i = 0; i < ITER; ++i) {
      int c = i * 256 + t;
      int n = c / (BM / 8), rest = c % (BM / 8);
      int zi = rest >> 3, cc = (rest & 7) * 8;
      long dst = ((long)((m0 >> 6) + zi) * 1024 + n0 + n) * 64 + cc;
      *(f16x8*)(Ch + dst) = *(const f16x8*)(ct + n * BM + zi * 64 + cc);
    }
  } else {  // OUT == 2
    constexpr int ITER = BM * (BN / 8) / 256;
    #pragma unroll
    for (int i = 0; i < ITER; ++i) {
      int c = i * 256 + t;
      int ml = c / (BN / 8), cc = (c % (BN / 8)) * 8;
      long dst = (long)z * sC + (long)(m0 + ml) * ldC + n0 + cc;
      *(f16x8*)(Ch + dst) = *(const f16x8*)(ct + ml * BN + cc);
    }
  }
}

// ---------------- g1: Pcat (128x64) || P3T (128x64), 768 blocks, natural, BK=128 ----------------
// A = Q fp32 row-major reg-staged; B = W11 fp32 row-major (bx<16) or prep'd fp16 transposed.

__global__ __launch_bounds__(256) void g1_kernel(
    const float* __restrict__ Qf, const float* __restrict__ W11,
    const unsigned short* __restrict__ W12T, const unsigned short* __restrict__ W21T,
    unsigned short* __restrict__ Pcat, unsigned short* __restrict__ P3T)
{
  __shared__ char smem[49152];
  int bid = blockIdx.x;  // natural order: round-robin across XCDs
  if (bid < 512) {   // Pcat: M=2048,N=2048,K=1024, tile 128x64
    int bx = bid & 31, by = bid >> 5;
    if (bx < 16)
      gemm_body<128, 64, 1, 1, 1, 4>(smem, bx, by, 0,
          nullptr, Qf, nullptr, W11, nullptr, Pcat,
          2048, 2048, 1024, 1024, 1024, 0, 0, 0, 0, bx * 64);
    else
      gemm_body<128, 64, 1, 1, 0, 4>(smem, bx, by, 0,
          nullptr, Qf, W12T, nullptr, nullptr, Pcat,
          2048, 2048, 1024, 1024, 1024, 0, 0, 0, 0, (bx - 16) * 64);
  } else {           // P3T: M=2048,N=1024,K=1024
    int b2 = bid - 512;
    gemm_body<128, 64, 3, 1, 0, 4>(smem, b2 & 15, b2 >> 4, 0,
        nullptr, Qf, W21T, nullptr, nullptr, P3T,
        2048, 1024, 1024, 1024, 1024, 0, 0, 0, 0, (b2 & 15) * 64);
  }
}

// ---------------- g2: scores, 32x128 full-K, BK=128, fused aq softmax ----------------

__global__ __launch_bounds__(512) void g2_kernel(
    const float* __restrict__ Afeat, const unsigned short* __restrict__ Pcat,
    unsigned short* __restrict__ aq, float* __restrict__ Spar)
{
  __shared__ char smem[40960];   // A: 4 x 2KB, B: 4 x 8KB
  auto Ac = [&](int c) { return smem + c * 2048; };
  auto Bc = [&](int c) { return smem + 8192 + c * 8192; };

  int orig = blockIdx.x;            // 512 blocks; z-grouped for Pcat L2 residence
  int xcd = orig & 7, idx = orig >> 3;
  int z   = xcd * 4 + (idx >> 4);
  int mt  = idx & 15;
  const int m0 = mt * 32;
  const int t = threadIdx.x, lane = t & 63;
  const int wid = t >> 6, wr = wid >> 2, wc = wid & 3;  // 2 x 4 waves

  const float* Ab = Afeat + (long)z * 524288;
  const unsigned short* Bb = Pcat + (long)z * 131072;

  f32x4 acc[2];
  acc[0] = f32x4{0.f, 0.f, 0.f, 0.f};
  acc[1] = f32x4{0.f, 0.f, 0.f, 0.f};

  auto ldfrag = [&](const char* lbuf, int rr) -> f16x8 {
    int ob = rr * 64 + (lane >> 4) * 16;
    ob ^= ((ob >> 7) & 3) << 4;
    return *(const f16x8*)(lbuf + ob);
  };
  auto stageA2 = [&](int c0k, int k0) {  // chunks c0k, c0k+1: t<256 -> c0k, t>=256 -> c0k+1
    int half = t >> 8, tt = t & 255;
    int ob = tt * 8;
    int e  = ob ^ (((ob >> 7) & 3) << 4);
    int m  = e >> 6, ke = (e & 63) >> 1;
    float4 v = *(const float4*)(Ab + (long)(m0 + m) * 1024 + k0 + half * 32 + ke);
    ushort4 h;
    h.x = f2h(v.x); h.y = f2h(v.y); h.z = f2h(v.z); h.w = f2h(v.w);
    *(ushort4*)(Ac(c0k + half) + ob) = h;
  };
  auto stageB = [&](int c, int k0) {
    int ob = t * 16;
    int e  = ob ^ (((ob >> 7) & 3) << 4);
    int n  = e >> 6, kk = (e & 63) >> 1;
    const unsigned short* gp = Bb + (long)n * 1024 + k0 + kk;
    char* lp = Bc(c) + (t & ~63) * 16;
    __builtin_amdgcn_global_load_lds((gas_t)(const void*)gp, (las_t)(void*)lp, 16, 0, 0);
  };
  auto compute32 = [&](const char* Aq, const char* Bq) {
    f16x8 ah = ldfrag(Aq, wr * 16 + (lane & 15));
    #pragma unroll
    for (int ni = 0; ni < 2; ++ni) {
      f16x8 bh = ldfrag(Bq, wc * 32 + ni * 16 + (lane & 15));
      acc[ni] = __builtin_amdgcn_mfma_f32_16x16x32_f16(ah, bh, acc[ni], 0, 0, 0);
    }
  };

  for (int k0 = 0; k0 < 1024; k0 += 128) {
    stageA2(0, k0);
    stageA2(2, k0 + 64);
    #pragma unroll
    for (int c = 0; c < 4; ++c) stageB(c, k0 + 32 * c);
    __syncthreads();
    #pragma unroll
    for (int c = 0; c < 4; ++c) compute32(Ac(c), Bc(c));
    __syncthreads();
  }

  // epilogue: gather full rows in LDS, fused aq row-softmax, qa half -> Spar fp32
  float* red = (float*)smem;  // [32][128] = 16KB
  #pragma unroll
  for (int ni = 0; ni < 2; ++ni)
    #pragma unroll
    for (int r = 0; r < 4; ++r) {
      int lrow = wr * 16 + (lane >> 4) * 4 + r;
      int col  = wc * 32 + ni * 16 + (lane & 15);
      red[lrow * 128 + col] = acc[ni][r];
    }
  __syncthreads();

  int row = t >> 4, cg = (t & 15) * 4;   // 16 threads per row, 4 cols each
  float a0 = red[row * 128 + cg],     a1 = red[row * 128 + cg + 1];
  float a2 = red[row * 128 + cg + 2], a3 = red[row * 128 + cg + 3];
  float4 vq = *(float4*)&red[row * 128 + 64 + cg];
  float mx = fmaxf(fmaxf(a0, a1), fmaxf(a2, a3));
  #pragma unroll
  for (int off = 8; off; off >>= 1) mx = fmaxf(mx, __shfl_xor(mx, off));
  float e0 = __expf(a0 - mx), e1 = __expf(a1 - mx);
  float e2 = __expf(a2 - mx), e3 = __expf(a3 - mx);
  float s = (e0 + e1) + (e2 + e3);
  #pragma unroll
  for (int off = 8; off; off >>= 1) s += __shfl_xor(s, off);
  float inv = 1.0f / s;
  ushort4 h;
  h.x = f2h(e0 * inv); h.y = f2h(e1 * inv); h.z = f2h(e2 * inv); h.w = f2h(e3 * inv);
  long base = (long)z * 32768 + (long)(m0 + row) * 64 + cg;
  *(ushort4*)(aq + base) = h;
  *(float4*)(Spar + base) = vq;
}

// ---------------- qa col-softmax ----------------

__global__ __launch_bounds__(256) void softmax_cols(const float* __restrict__ Sp,
                                                    unsigned short* __restrict__ qa)
{
  int bq = blockIdx.x;
  int b = bq >> 6, q = bq & 63;
  int t = threadIdx.x;
  const float* base = Sp + (long)b * 32768 + q;
  float v0 = base[(long)t * 64];
  float v1 = base[(long)(t + 256) * 64];
  float m = fmaxf(v0, v1);
  #pragma unroll
  for (int off = 32; off; off >>= 1) m = fmaxf(m, __shfl_xor(m, off));
  __shared__ float sm[4], ss[4];
  int wid = t >> 6, lane = t & 63;
  if (lane == 0) sm[wid] = m;
  __syncthreads();
  float M = fmaxf(fmaxf(sm[0], sm[1]), fmaxf(sm[2], sm[3]));
  float e0 = __expf(v0 - M), e1 = __expf(v1 - M);
  float s = e0 + e1;
  #pragma unroll
  for (int off = 32; off; off >>= 1) s += __shfl_xor(s, off);
  if (lane == 0) ss[wid] = s;
  __syncthreads();
  float inv = 1.0f / ((ss[0] + ss[1]) + (ss[2] + ss[3]));
  qa[(long)bq * 512 + t]       = f2h(e0 * inv);
  qa[(long)bq * 512 + t + 256] = f2h(e1 * inv);
}

// ---------------- g3: PmaxA (LDS-free, K=64) || ctx (BK=64), natural order ----------------

__global__ __launch_bounds__(256) void g3_kernel(
    const unsigned short* aq, const unsigned short* P3T, float* PmaxA,
    const unsigned short* qa, const float* Afeat, unsigned short* ctx)
{
  __shared__ char smem[16384];
  int bid = blockIdx.x;  // natural order (heterogeneous work types)
  if (bid < 1024) {
    // PmaxA: per batch M=512,N=1024,K=64, tile 128x128, fragments direct from global
    int bx = bid & 7, by = (bid >> 3) & 3, z = bid >> 5;
    int n0 = bx * 128, m0 = by * 128;
    const unsigned short* Aq = aq + (long)z * 32768;
    const unsigned short* Bp = P3T + (long)z * 65536;
    const int t = threadIdx.x, lane = t & 63;
    const int wid = t >> 6, wr = wid >> 1, wc = wid & 1;

    f32x4 acc[4][4];
    #pragma unroll
    for (int i = 0; i < 4; ++i)
      #pragma unroll
      for (int j = 0; j < 4; ++j)
        acc[i][j] = f32x4{0.f, 0.f, 0.f, 0.f};

    #pragma unroll
    for (int c = 0; c < 2; ++c) {
      f16x8 ah[4];
      #pragma unroll
      for (int mi = 0; mi < 4; ++mi) {
        int row = m0 + wr * 64 + mi * 16 + (lane & 15);
        ah[mi] = *(const f16x8*)(Aq + (long)row * 64 + c * 32 + (lane >> 4) * 8);
      }
      #pragma unroll
      for (int ni = 0; ni < 4; ++ni) {
        int rc = n0 + wc * 64 + ni * 16 + (lane & 15);
        f16x8 bh = *(const f16x8*)(Bp + (long)rc * 64 + c * 32 + (lane >> 4) * 8);
        #pragma unroll
        for (int mi = 0; mi < 4; ++mi)
          acc[mi][ni] = __builtin_amdgcn_mfma_f32_16x16x32_f16(ah[mi], bh, acc[mi][ni], 0, 0, 0);
      }
    }

    float* red = (float*)smem;  // [8][128] = 4KB
    #pragma unroll
    for (int ni = 0; ni < 4; ++ni) {
      float pm = 0.0f;  // relu floor
      #pragma unroll
      for (int mi = 0; mi < 4; ++mi)
        #pragma unroll
        for (int r = 0; r < 4; ++r)
          pm = fmaxf(pm, acc[mi][ni][r]);
      int g = wr * 4 + (lane >> 4);
      int col = wc * 64 + ni * 16 + (lane & 15);
      red[g * 128 + col] = pm;
    }
    __syncthreads();
    if (t < 128) {
      float m = red[t];
      #pragma unroll
      for (int g = 1; g < 8; ++g) m = fmaxf(m, red[g * 128 + t]);
      PmaxA[(long)(z * 4 + by) * 1024 + n0 + t] = m;
    }
  } else {           // ctx: per batch M=64,N=1024,K=512, tile 64x64, B = Afeat fp32 k-major
    int b2 = bid - 1024;
    gemm_body<64, 64, 2, 0, 2, 2>(smem, b2 & 15, 0, b2 >> 4,
        qa, nullptr, nullptr, Afeat, nullptr, ctx,
        64, 1024, 512, 512, 1024, 1024, 32768L, 524288L, 65536L, (b2 & 15) * 64);
  }
}

// ---------------- g4: PmaxQ colmax + fused final combine, BK=128 ----------------

__global__ __launch_bounds__(256) void g4_kernel(
    const unsigned short* ctx, const unsigned short* W22T,
    const float* PmaxA, float* out)
{
  __shared__ char smem[32768];
  gemm_body<64, 64, 6, 0, 0, 4>(smem, blockIdx.x, blockIdx.y, 0,
      ctx, nullptr, W22T, PmaxA, out, nullptr,
      2048, 1024, 1024, 1024, 1024, 1024, 0, 0, 0, blockIdx.x * 64);
}

// ---------------- launch ----------------

extern "C" void kernel_launch(void* const* d_in, const int* in_sizes, int n_in,
                              void* d_out, int out_size, void* d_ws, size_t ws_size,
                              hipStream_t stream) {
  const float* Afeat = (const float*)d_in[0];
  const float* Qfeat = (const float*)d_in[1];
  const float* W11   = (const float*)d_in[2];
  const float* W12   = (const float*)d_in[3];
  const float* W21   = (const float*)d_in[4];
  const float* W22   = (const float*)d_in[5];
  float* out = (float*)d_out;

  char* w = (char*)d_ws;
  auto alloc = [&](long bytes) { char* p = w; w += bytes; return p; };
  unsigned short* W12T  = (unsigned short*)alloc(2097152);
  unsigned short* W21T  = (unsigned short*)alloc(2097152);
  unsigned short* W22T  = (unsigned short*)alloc(2097152);
  unsigned short* Pcat  = (unsigned short*)alloc(8388608);   // [32][128][1024]
  unsigned short* P3T   = (unsigned short*)alloc(4194304);   // [32][1024][64]
  float*          Spar  = (float*)alloc(4194304);            // [32][512][64] qa scores
  unsigned short* aq    = (unsigned short*)alloc(2097152);   // [32][512][64]
  unsigned short* qa    = (unsigned short*)alloc(2097152);   // [32][64][512]
  unsigned short* ctx   = (unsigned short*)alloc(4194304);   // [32][64][1024]
  float*          PmaxA = (float*)alloc(524288);             // [128][1024]

  dim3 blk(256), tblk(32, 8);

  prep_W3<<<dim3(32, 32, 3), tblk, 0, stream>>>(W12, W21, W22, W12T, W21T, W22T);
  g1_kernel<<<768, blk, 0, stream>>>(Qfeat, W11, W12T, W21T, Pcat, P3T);
  g2_kernel<<<512, dim3(512), 0, stream>>>(Afeat, Pcat, aq, Spar);
  softmax_cols<<<2048, blk, 0, stream>>>(Spar, qa);
  g3_kernel<<<1536, blk, 0, stream>>>(aq, P3T, PmaxA, qa, Afeat, ctx);
  g4_kernel<<<dim3(16, 32), blk, 0, stream>>>(ctx, W22T, PmaxA, out);
}

// Round 18
// 90.054 us; speedup vs baseline: 1.1775x; 1.1775x over previous
//
#include <hip/hip_runtime.h>
#include <stdint.h>

// B=32, La=512, Lq=64, H=1024. Plain-fp16 pipeline (absmax 0.0078 vs thr 0.0456).
// R16 configuration (best: 90.4 us). prep'd fp16 weights + global_load_lds staging
// (R14/R17 both showed inline fp32 staging in g1 is strictly worse).
// prep_all: Wcat/W21T/W22T (z<4) + Q->fp16 (z>=4)
// g1: Pcat = Q@Wcat^T (128x64, remap) || P3T = (Q@W21)^T (128x64) [768 blocks] BK=128
// g2: scores = A@Pcat^T, 32x128 full-K BK=128; fused aq row-softmax; qa -> Spar fp32
// softmax_cols: qa = colsoftmax(Spar) fp16
// g3: PmaxA = colmax(relu(aq@P3T^T)) LDS-free (K=64) || ctx = qa@A (BK=64)
// g4: PmaxQ = colmax64(relu(ctx@W22T^T)) + fused final combine  (BK=128)

using f16x8 = __attribute__((ext_vector_type(8))) _Float16;
using f32x4 = __attribute__((ext_vector_type(4))) float;
typedef const __attribute__((address_space(1))) void* gas_t;
typedef __attribute__((address_space(3))) void* las_t;

__device__ __forceinline__ unsigned short f2h(float x) {
  _Float16 h = (_Float16)x;
  return __builtin_bit_cast(unsigned short, h);
}

// ---------------- prep: z<4 -> W conversions; z>=4 -> Q fp32->fp16 ----------------

__global__ __launch_bounds__(256) void prep_all(
    const float* __restrict__ W11, const float* __restrict__ W12,
    const float* __restrict__ W21, const float* __restrict__ W22,
    const float* __restrict__ Qfeat,
    unsigned short* __restrict__ Wcat, unsigned short* __restrict__ W21T,
    unsigned short* __restrict__ W22T, unsigned short* __restrict__ Q_hi)
{
  int z = blockIdx.z;
  int tx = threadIdx.x, ty = threadIdx.y;
  if (z >= 4) {  // Q: 524288 float4 groups over 2048 virtual blocks
    int blk = (z - 4) * 1024 + blockIdx.y * 32 + blockIdx.x;
    int i = blk * 256 + ty * 32 + tx;
    float4 v = ((const float4*)Qfeat)[i];
    ushort4 h;
    h.x = f2h(v.x); h.y = f2h(v.y); h.z = f2h(v.z); h.w = f2h(v.w);
    ((ushort4*)Q_hi)[i] = h;
    return;
  }
  __shared__ float tile[32][33];
  const float* src = z == 0 ? W11 : z == 1 ? W12 : z == 2 ? W21 : W22;
  int r0 = blockIdx.y * 32, c0 = blockIdx.x * 32;
  #pragma unroll
  for (int i = 0; i < 4; ++i) {
    int r = r0 + ty + i * 8;
    float v = src[(long)r * 1024 + c0 + tx];
    tile[ty + i * 8][tx] = v;
    if (z == 0) Wcat[(long)r * 1024 + c0 + tx] = f2h(v);
  }
  __syncthreads();
  if (z > 0) {
    #pragma unroll
    for (int i = 0; i < 4; ++i) {
      float v = tile[tx][ty + i * 8];
      long o = (long)(c0 + ty + i * 8) * 1024 + r0 + tx;
      if (z == 1)      Wcat[1048576 + o] = f2h(v);
      else if (z == 2) W21T[o] = f2h(v);
      else             W22T[o] = f2h(v);
    }
  }
}

// ---------------- generic MFMA GEMM body (C = A @ B^T), NC x 32-k chunks, fp16 ----------------
// OUT: 1=Pcat remap, 2=fp16 batched, 3=transpose remap, 6=relu+colmax64+final.
// BF32: B operand fp32 [K x ldB] k-major, staged->fp16.
// OUT 1/2/3 use LDS-gathered coalesced 16B stores (bit-identical values).
template<int BM, int BN, int OUT, bool BF32, int NC>
__device__ __forceinline__ void gemm_body(
    char* smem, int bx, int by, int z,
    const unsigned short* __restrict__ Ah,
    const unsigned short* __restrict__ Bh, const float* __restrict__ Bf,
    float* __restrict__ Cf, unsigned short* __restrict__ Ch,
    int M, int N, int K, int ldA, int ldB, int ldC, long sA, long sB, long sC)
{
  constexpr int ACH = BM * 64, BCH = BN * 64;  // bytes per 32-k chunk
  constexpr int MI = BM / 32, NI = BN / 32;
  char* As = smem;
  char* Bs = smem + NC * ACH;

  const int m0 = by * BM, n0 = bx * BN;
  const int t = threadIdx.x, lane = t & 63;
  const int wid = t >> 6, wr = wid >> 1, wc = wid & 1;

  const unsigned short* Ab = Ah + (long)z * sA;
  const unsigned short* Bb = BF32 ? nullptr : Bh + (long)z * sB;
  const float* Bfb = BF32 ? Bf + (long)z * sB : nullptr;

  f32x4 acc[MI][NI];
  #pragma unroll
  for (int i = 0; i < MI; ++i)
    #pragma unroll
    for (int j = 0; j < NI; ++j)
      acc[i][j] = f32x4{0.f, 0.f, 0.f, 0.f};

  auto stage4k = [&](char* lbuf, const unsigned short* g, int ld, int row0, int k0, int rmax) {
    int ob = t * 16;
    int e  = ob ^ (((ob >> 7) & 3) << 4);
    int m  = e >> 6, k = (e & 63) >> 1;
    int row = row0 + m; row = row < rmax ? row : rmax - 1;
    const unsigned short* gp = g + (long)row * ld + k0 + k;
    char* lp = lbuf + (t & ~63) * 16;  // wave-uniform; HW adds lane*16
    __builtin_amdgcn_global_load_lds((gas_t)(const void*)gp, (las_t)(void*)lp, 16, 0, 0);
  };
  auto stageB_f32 = [&](char* lbuf, const float* g, int ld, int nb, int k0) {
    int ob = t * 16;
    int e  = ob ^ (((ob >> 7) & 3) << 4);
    int n  = e >> 6, kb = (e & 63) >> 1;
    f16x8 pk;
    #pragma unroll
    for (int j = 0; j < 8; ++j) {
      float v = g[(long)(k0 + kb + j) * ld + nb + n];
      pk[j] = (_Float16)v;
    }
    *(f16x8*)(lbuf + ob) = pk;
  };
  auto ldfrag = [&](const char* lbuf, int rr) -> f16x8 {
    int ob = rr * 64 + (lane >> 4) * 16;
    ob ^= ((ob >> 7) & 3) << 4;
    return *(const f16x8*)(lbuf + ob);
  };
  auto compute32 = [&](const char* Ac, const char* Bc) {
    f16x8 ah[MI];
    #pragma unroll
    for (int mi = 0; mi < MI; ++mi)
      ah[mi] = ldfrag(Ac, wr * (BM / 2) + mi * 16 + (lane & 15));
    #pragma unroll
    for (int ni = 0; ni < NI; ++ni) {
      f16x8 bh = ldfrag(Bc, wc * (BN / 2) + ni * 16 + (lane & 15));
      #pragma unroll
      for (int mi = 0; mi < MI; ++mi)
        acc[mi][ni] = __builtin_amdgcn_mfma_f32_16x16x32_f16(ah[mi], bh, acc[mi][ni], 0, 0, 0);
    }
  };

  for (int k0 = 0; k0 < K; k0 += 32 * NC) {
    #pragma unroll
    for (int c = 0; c < NC; ++c) {
      stage4k(As + c * ACH, Ab, ldA, m0, k0 + 32 * c, M);
      if (BM == 128) stage4k(As + c * ACH + 4096, Ab, ldA, m0 + 64, k0 + 32 * c, M);
    }
    #pragma unroll
    for (int c = 0; c < NC; ++c) {
      if (BF32) stageB_f32(Bs + c * BCH, Bfb, ldB, n0, k0 + 32 * c);
      else      stage4k(Bs + c * BCH, Bb, ldB, n0, k0 + 32 * c, N);
    }
    __syncthreads();
    #pragma unroll
    for (int c = 0; c < NC; ++c) compute32(As + c * ACH, Bs + c * BCH);
    __syncthreads();
  }

  if (OUT == 6) {
    float* red = (float*)smem;  // safe: k-loop ended with __syncthreads
    #pragma unroll
    for (int ni = 0; ni < NI; ++ni) {
      float pm = 0.0f;  // relu floor
      #pragma unroll
      for (int mi = 0; mi < MI; ++mi)
        #pragma unroll
        for (int r = 0; r < 4; ++r)
          pm = fmaxf(pm, acc[mi][ni][r]);
      int g = wr * 4 + (lane >> 4);
      int col = wc * (BN / 2) + ni * 16 + (lane & 15);
      red[g * BN + col] = pm;
    }
    __syncthreads();
    if (t < BN) {  // BM=BN=64, by = batch; Bf = PmaxA [128][1024]; Cf = out
      float pq = red[t];
      #pragma unroll
      for (int g = 1; g < 8; ++g) pq = fmaxf(pq, red[g * BN + t]);
      float pa = Bf[(long)(by * 4) * 1024 + n0 + t];
      #pragma unroll
      for (int mt = 1; mt < 4; ++mt)
        pa = fmaxf(pa, Bf[(long)(by * 4 + mt) * 1024 + n0 + t]);
      Cf[(long)by * 1024 + n0 + t] = 0.5f * pa + 0.5f * pq;
    }
    return;
  }

  // OUT 1/2/3: stage C-tile to LDS fp16, then coalesced 16B stores.
  unsigned short* ct = (unsigned short*)smem;  // [BM][BN] (OUT 1/2) or [BN][BM] (OUT 3)
  #pragma unroll
  for (int mi = 0; mi < MI; ++mi)
    #pragma unroll
    for (int r = 0; r < 4; ++r) {
      int ml = wr * (BM / 2) + mi * 16 + (lane >> 4) * 4 + r;
      #pragma unroll
      for (int ni = 0; ni < NI; ++ni) {
        int nl = wc * (BN / 2) + ni * 16 + (lane & 15);
        unsigned short hv = f2h(acc[mi][ni][r]);
        if (OUT == 3) ct[nl * BM + ml] = hv;
        else          ct[ml * BN + nl] = hv;
      }
    }
  __syncthreads();

  if (OUT == 1) {
    constexpr int ITER = BM * (BN / 8) / 256;
    #pragma unroll
    for (int i = 0; i < ITER; ++i) {
      int c = i * 256 + t;
      int ml = c / (BN / 8), cc = (c % (BN / 8)) * 8;
      int gm = m0 + ml;
      int b = gm >> 6, q = gm & 63;
      long dst = (long)b * 131072 + (long)((n0 >> 10) * 64 + q) * 1024 + (n0 & 1023) + cc;
      *(f16x8*)(Ch + dst) = *(const f16x8*)(ct + ml * BN + cc);
    }
  } else if (OUT == 3) {
    constexpr int ITER = BN * (BM / 8) / 256;
    #pragma unroll
    for (int i = 0; i < ITER; ++i) {
      int c = i * 256 + t;
      int n = c / (BM / 8), rest = c % (BM / 8);
      int zi = rest >> 3, cc = (rest & 7) * 8;
      long dst = ((long)((m0 >> 6) + zi) * 1024 + n0 + n) * 64 + cc;
      *(f16x8*)(Ch + dst) = *(const f16x8*)(ct + n * BM + zi * 64 + cc);
    }
  } else {  // OUT == 2
    constexpr int ITER = BM * (BN / 8) / 256;
    #pragma unroll
    for (int i = 0; i < ITER; ++i) {
      int c = i * 256 + t;
      int ml = c / (BN / 8), cc = (c % (BN / 8)) * 8;
      long dst = (long)z * sC + (long)(m0 + ml) * ldC + n0 + cc;
      *(f16x8*)(Ch + dst) = *(const f16x8*)(ct + ml * BN + cc);
    }
  }
}

// ---------------- g1: Pcat (128x64) || P3T (128x64), 768 blocks, natural, BK=128 ----------------

__global__ __launch_bounds__(256) void g1_kernel(
    const unsigned short* Q_hi, const unsigned short* Wcat, const unsigned short* W21T,
    unsigned short* Pcat, unsigned short* P3T)
{
  __shared__ char smem[49152];
  int bid = blockIdx.x;  // natural order: round-robin across XCDs
  if (bid < 512) {   // Pcat: M=2048,N=2048,K=1024, tile 128x64
    gemm_body<128, 64, 1, false, 4>(smem, bid & 31, bid >> 5, 0,
        Q_hi, Wcat, nullptr, nullptr, Pcat,
        2048, 2048, 1024, 1024, 1024, 0, 0, 0, 0);
  } else {           // P3T: M=2048,N=1024,K=1024, tile 128x64
    int b2 = bid - 512;
    gemm_body<128, 64, 3, false, 4>(smem, b2 & 15, b2 >> 4, 0,
        Q_hi, W21T, nullptr, nullptr, P3T,
        2048, 1024, 1024, 1024, 1024, 0, 0, 0, 0);
  }
}

// ---------------- g2: scores, 32x128 full-K, BK=128, fused aq softmax ----------------

__global__ __launch_bounds__(512) void g2_kernel(
    const float* __restrict__ Afeat, const unsigned short* __restrict__ Pcat,
    unsigned short* __restrict__ aq, float* __restrict__ Spar)
{
  __shared__ char smem[40960];   // A: 4 x 2KB, B: 4 x 8KB
  auto Ac = [&](int c) { return smem + c * 2048; };
  auto Bc = [&](int c) { return smem + 8192 + c * 8192; };

  int orig = blockIdx.x;            // 512 blocks; z-grouped for Pcat L2 residence
  int xcd = orig & 7, idx = orig >> 3;
  int z   = xcd * 4 + (idx >> 4);
  int mt  = idx & 15;
  const int m0 = mt * 32;
  const int t = threadIdx.x, lane = t & 63;
  const int wid = t >> 6, wr = wid >> 2, wc = wid & 3;  // 2 x 4 waves

  const float* Ab = Afeat + (long)z * 524288;
  const unsigned short* Bb = Pcat + (long)z * 131072;

  f32x4 acc[2];
  acc[0] = f32x4{0.f, 0.f, 0.f, 0.f};
  acc[1] = f32x4{0.f, 0.f, 0.f, 0.f};

  auto ldfrag = [&](const char* lbuf, int rr) -> f16x8 {
    int ob = rr * 64 + (lane >> 4) * 16;
    ob ^= ((ob >> 7) & 3) << 4;
    return *(const f16x8*)(lbuf + ob);
  };
  auto stageA2 = [&](int c0k, int k0) {  // chunks c0k, c0k+1: t<256 -> c0k, t>=256 -> c0k+1
    int half = t >> 8, tt = t & 255;
    int ob = tt * 8;
    int e  = ob ^ (((ob >> 7) & 3) << 4);
    int m  = e >> 6, ke = (e & 63) >> 1;
    float4 v = *(const float4*)(Ab + (long)(m0 + m) * 1024 + k0 + half * 32 + ke);
    ushort4 h;
    h.x = f2h(v.x); h.y = f2h(v.y); h.z = f2h(v.z); h.w = f2h(v.w);
    *(ushort4*)(Ac(c0k + half) + ob) = h;
  };
  auto stageB = [&](int c, int k0) {
    int ob = t * 16;
    int e  = ob ^ (((ob >> 7) & 3) << 4);
    int n  = e >> 6, kk = (e & 63) >> 1;
    const unsigned short* gp = Bb + (long)n * 1024 + k0 + kk;
    char* lp = Bc(c) + (t & ~63) * 16;
    __builtin_amdgcn_global_load_lds((gas_t)(const void*)gp, (las_t)(void*)lp, 16, 0, 0);
  };
  auto compute32 = [&](const char* Aq, const char* Bq) {
    f16x8 ah = ldfrag(Aq, wr * 16 + (lane & 15));
    #pragma unroll
    for (int ni = 0; ni < 2; ++ni) {
      f16x8 bh = ldfrag(Bq, wc * 32 + ni * 16 + (lane & 15));
      acc[ni] = __builtin_amdgcn_mfma_f32_16x16x32_f16(ah, bh, acc[ni], 0, 0, 0);
    }
  };

  for (int k0 = 0; k0 < 1024; k0 += 128) {
    stageA2(0, k0);
    stageA2(2, k0 + 64);
    #pragma unroll
    for (int c = 0; c < 4; ++c) stageB(c, k0 + 32 * c);
    __syncthreads();
    #pragma unroll
    for (int c = 0; c < 4; ++c) compute32(Ac(c), Bc(c));
    __syncthreads();
  }

  // epilogue: gather full rows in LDS, fused aq row-softmax, qa half -> Spar fp32
  float* red = (float*)smem;  // [32][128] = 16KB
  #pragma unroll
  for (int ni = 0; ni < 2; ++ni)
    #pragma unroll
    for (int r = 0; r < 4; ++r) {
      int lrow = wr * 16 + (lane >> 4) * 4 + r;
      int col  = wc * 32 + ni * 16 + (lane & 15);
      red[lrow * 128 + col] = acc[ni][r];
    }
  __syncthreads();

  int row = t >> 4, cg = (t & 15) * 4;   // 16 threads per row, 4 cols each
  float a0 = red[row * 128 + cg],     a1 = red[row * 128 + cg + 1];
  float a2 = red[row * 128 + cg + 2], a3 = red[row * 128 + cg + 3];
  float4 vq = *(float4*)&red[row * 128 + 64 + cg];
  float mx = fmaxf(fmaxf(a0, a1), fmaxf(a2, a3));
  #pragma unroll
  for (int off = 8; off; off >>= 1) mx = fmaxf(mx, __shfl_xor(mx, off));
  float e0 = __expf(a0 - mx), e1 = __expf(a1 - mx);
  float e2 = __expf(a2 - mx), e3 = __expf(a3 - mx);
  float s = (e0 + e1) + (e2 + e3);
  #pragma unroll
  for (int off = 8; off; off >>= 1) s += __shfl_xor(s, off);
  float inv = 1.0f / s;
  ushort4 h;
  h.x = f2h(e0 * inv); h.y = f2h(e1 * inv); h.z = f2h(e2 * inv); h.w = f2h(e3 * inv);
  long base = (long)z * 32768 + (long)(m0 + row) * 64 + cg;
  *(ushort4*)(aq + base) = h;
  *(float4*)(Spar + base) = vq;
}

// ---------------- qa col-softmax ----------------

__global__ __launch_bounds__(256) void softmax_cols(const float* __restrict__ Sp,
                                                    unsigned short* __restrict__ qa)
{
  int bq = blockIdx.x;
  int b = bq >> 6, q = bq & 63;
  int t = threadIdx.x;
  const float* base = Sp + (long)b * 32768 + q;
  float v0 = base[(long)t * 64];
  float v1 = base[(long)(t + 256) * 64];
  float m = fmaxf(v0, v1);
  #pragma unroll
  for (int off = 32; off; off >>= 1) m = fmaxf(m, __shfl_xor(m, off));
  __shared__ float sm[4], ss[4];
  int wid = t >> 6, lane = t & 63;
  if (lane == 0) sm[wid] = m;
  __syncthreads();
  float M = fmaxf(fmaxf(sm[0], sm[1]), fmaxf(sm[2], sm[3]));
  float e0 = __expf(v0 - M), e1 = __expf(v1 - M);
  float s = e0 + e1;
  #pragma unroll
  for (int off = 32; off; off >>= 1) s += __shfl_xor(s, off);
  if (lane == 0) ss[wid] = s;
  __syncthreads();
  float inv = 1.0f / ((ss[0] + ss[1]) + (ss[2] + ss[3]));
  qa[(long)bq * 512 + t]       = f2h(e0 * inv);
  qa[(long)bq * 512 + t + 256] = f2h(e1 * inv);
}

// ---------------- g3: PmaxA (LDS-free, K=64) || ctx (BK=64), natural order ----------------

__global__ __launch_bounds__(256) void g3_kernel(
    const unsigned short* aq, const unsigned short* P3T, float* PmaxA,
    const unsigned short* qa, const float* Afeat, unsigned short* ctx)
{
  __shared__ char smem[16384];
  int bid = blockIdx.x;  // natural order (heterogeneous work types)
  if (bid < 1024) {
    // PmaxA: per batch M=512,N=1024,K=64, tile 128x128, fragments direct from global
    int bx = bid & 7, by = (bid >> 3) & 3, z = bid >> 5;
    int n0 = bx * 128, m0 = by * 128;
    const unsigned short* Aq = aq + (long)z * 32768;
    const unsigned short* Bp = P3T + (long)z * 65536;
    const int t = threadIdx.x, lane = t & 63;
    const int wid = t >> 6, wr = wid >> 1, wc = wid & 1;

    f32x4 acc[4][4];
    #pragma unroll
    for (int i = 0; i < 4; ++i)
      #pragma unroll
      for (int j = 0; j < 4; ++j)
        acc[i][j] = f32x4{0.f, 0.f, 0.f, 0.f};

    #pragma unroll
    for (int c = 0; c < 2; ++c) {
      f16x8 ah[4];
      #pragma unroll
      for (int mi = 0; mi < 4; ++mi) {
        int row = m0 + wr * 64 + mi * 16 + (lane & 15);
        ah[mi] = *(const f16x8*)(Aq + (long)row * 64 + c * 32 + (lane >> 4) * 8);
      }
      #pragma unroll
      for (int ni = 0; ni < 4; ++ni) {
        int rc = n0 + wc * 64 + ni * 16 + (lane & 15);
        f16x8 bh = *(const f16x8*)(Bp + (long)rc * 64 + c * 32 + (lane >> 4) * 8);
        #pragma unroll
        for (int mi = 0; mi < 4; ++mi)
          acc[mi][ni] = __builtin_amdgcn_mfma_f32_16x16x32_f16(ah[mi], bh, acc[mi][ni], 0, 0, 0);
      }
    }

    float* red = (float*)smem;  // [8][128] = 4KB
    #pragma unroll
    for (int ni = 0; ni < 4; ++ni) {
      float pm = 0.0f;  // relu floor
      #pragma unroll
      for (int mi = 0; mi < 4; ++mi)
        #pragma unroll
        for (int r = 0; r < 4; ++r)
          pm = fmaxf(pm, acc[mi][ni][r]);
      int g = wr * 4 + (lane >> 4);
      int col = wc * 64 + ni * 16 + (lane & 15);
      red[g * 128 + col] = pm;
    }
    __syncthreads();
    if (t < 128) {
      float m = red[t];
      #pragma unroll
      for (int g = 1; g < 8; ++g) m = fmaxf(m, red[g * 128 + t]);
      PmaxA[(long)(z * 4 + by) * 1024 + n0 + t] = m;
    }
  } else {           // ctx: per batch M=64,N=1024,K=512, tile 64x64, B = A fp32 (k-major)
    int b2 = bid - 1024;
    gemm_body<64, 64, 2, true, 2>(smem, b2 & 15, 0, b2 >> 4,
        qa, nullptr, Afeat, nullptr, ctx,
        64, 1024, 512, 512, 1024, 1024, 32768L, 524288L, 65536L);
  }
}

// ---------------- g4: PmaxQ colmax + fused final combine, BK=128 ----------------

__global__ __launch_bounds__(256) void g4_kernel(
    const unsigned short* ctx, const unsigned short* W22T,
    const float* PmaxA, float* out)
{
  __shared__ char smem[32768];
  gemm_body<64, 64, 6, false, 4>(smem, blockIdx.x, blockIdx.y, 0,
      ctx, W22T, PmaxA, out, nullptr,
      2048, 1024, 1024, 1024, 1024, 1024, 0, 0, 0);
}

// ---------------- launch ----------------

extern "C" void kernel_launch(void* const* d_in, const int* in_sizes, int n_in,
                              void* d_out, int out_size, void* d_ws, size_t ws_size,
                              hipStream_t stream) {
  const float* Afeat = (const float*)d_in[0];
  const float* Qfeat = (const float*)d_in[1];
  const float* W11   = (const float*)d_in[2];
  const float* W12   = (const float*)d_in[3];
  const float* W21   = (const float*)d_in[4];
  const float* W22   = (const float*)d_in[5];
  float* out = (float*)d_out;

  char* w = (char*)d_ws;
  auto alloc = [&](long bytes) { char* p = w; w += bytes; return p; };
  unsigned short* Q_hi  = (unsigned short*)alloc(4194304);
  unsigned short* Wcat  = (unsigned short*)alloc(4194304);   // [2048][1024] fp16: W11 ; W12^T
  unsigned short* W21T  = (unsigned short*)alloc(2097152);
  unsigned short* W22T  = (unsigned short*)alloc(2097152);
  unsigned short* Pcat  = (unsigned short*)alloc(8388608);   // [32][128][1024]
  unsigned short* P3T   = (unsigned short*)alloc(4194304);   // [32][1024][64]
  float*          Spar  = (float*)alloc(4194304);            // [32][512][64] qa scores
  unsigned short* aq    = (unsigned short*)alloc(2097152);   // [32][512][64]
  unsigned short* qa    = (unsigned short*)alloc(2097152);   // [32][64][512]
  unsigned short* ctx   = (unsigned short*)alloc(4194304);   // [32][64][1024]
  float*          PmaxA = (float*)alloc(524288);             // [128][1024]

  dim3 blk(256), tblk(32, 8);

  prep_all<<<dim3(32, 32, 6), tblk, 0, stream>>>(W11, W12, W21, W22, Qfeat,
                                                 Wcat, W21T, W22T, Q_hi);
  g1_kernel<<<768, blk, 0, stream>>>(Q_hi, Wcat, W21T, Pcat, P3T);
  g2_kernel<<<512, dim3(512), 0, stream>>>(Afeat, Pcat, aq, Spar);
  softmax_cols<<<2048, blk, 0, stream>>>(Spar, qa);
  g3_kernel<<<1536, blk, 0, stream>>>(aq, P3T, PmaxA, qa, Afeat, ctx);
  g4_kernel<<<dim3(16, 32), blk, 0, stream>>>(ctx, W22T, PmaxA, out);
}

// Round 20
// 88.881 us; speedup vs baseline: 1.1930x; 1.0132x over previous
//
#include <hip/hip_runtime.h>
#include <stdint.h>

// B=32, La=512, Lq=64, H=1024. Plain-fp16 pipeline (absmax 0.0078 vs thr 0.0456).
// R16/R18 config + g1 pipelined with counted vmcnt(6) + raw s_barrier, now with
// sched_barrier(0) pins at every sync edge (R19 raced: compiler hoisted loads/reads
// across the raw barrier — s_barrier is not a compiler memory fence).
// prep_all: Wcat/W21T/W22T (z<4) + Q->fp16 (z>=4)
// g1: Pcat = Q@Wcat^T (128x64, remap) || P3T = (Q@W21)^T (128x64) [768 blocks]
// g2: scores = A@Pcat^T, 32x128 full-K BK=128; fused aq row-softmax; qa -> Spar fp32
// softmax_cols: qa = colsoftmax(Spar) fp16
// g3: PmaxA = colmax(relu(aq@P3T^T)) LDS-free (K=64) || ctx = qa@A (BK=64)
// g4: PmaxQ = colmax64(relu(ctx@W22T^T)) + fused final combine  (BK=128)

using f16x8 = __attribute__((ext_vector_type(8))) _Float16;
using f32x4 = __attribute__((ext_vector_type(4))) float;
typedef const __attribute__((address_space(1))) void* gas_t;
typedef __attribute__((address_space(3))) void* las_t;

__device__ __forceinline__ unsigned short f2h(float x) {
  _Float16 h = (_Float16)x;
  return __builtin_bit_cast(unsigned short, h);
}

// ---------------- prep: z<4 -> W conversions; z>=4 -> Q fp32->fp16 ----------------

__global__ __launch_bounds__(256) void prep_all(
    const float* __restrict__ W11, const float* __restrict__ W12,
    const float* __restrict__ W21, const float* __restrict__ W22,
    const float* __restrict__ Qfeat,
    unsigned short* __restrict__ Wcat, unsigned short* __restrict__ W21T,
    unsigned short* __restrict__ W22T, unsigned short* __restrict__ Q_hi)
{
  int z = blockIdx.z;
  int tx = threadIdx.x, ty = threadIdx.y;
  if (z >= 4) {
    int blk = (z - 4) * 1024 + blockIdx.y * 32 + blockIdx.x;
    int i = blk * 256 + ty * 32 + tx;
    float4 v = ((const float4*)Qfeat)[i];
    ushort4 h;
    h.x = f2h(v.x); h.y = f2h(v.y); h.z = f2h(v.z); h.w = f2h(v.w);
    ((ushort4*)Q_hi)[i] = h;
    return;
  }
  __shared__ float tile[32][33];
  const float* src = z == 0 ? W11 : z == 1 ? W12 : z == 2 ? W21 : W22;
  int r0 = blockIdx.y * 32, c0 = blockIdx.x * 32;
  #pragma unroll
  for (int i = 0; i < 4; ++i) {
    int r = r0 + ty + i * 8;
    float v = src[(long)r * 1024 + c0 + tx];
    tile[ty + i * 8][tx] = v;
    if (z == 0) Wcat[(long)r * 1024 + c0 + tx] = f2h(v);
  }
  __syncthreads();
  if (z > 0) {
    #pragma unroll
    for (int i = 0; i < 4; ++i) {
      float v = tile[tx][ty + i * 8];
      long o = (long)(c0 + ty + i * 8) * 1024 + r0 + tx;
      if (z == 1)      Wcat[1048576 + o] = f2h(v);
      else if (z == 2) W21T[o] = f2h(v);
      else             W22T[o] = f2h(v);
    }
  }
}

// ---------------- pipelined GEMM body for g1 (C = A @ B^T), BM=128 BN=64 ----------------
// BK=64 double-buffer; 6 gload_lds per tile; counted vmcnt + raw barriers,
// sched_barrier(0)-pinned so the compiler cannot reorder across sync edges.
template<int OUT>
__device__ __forceinline__ void gemm_pipe(
    char* smem, int bx, int by,
    const unsigned short* __restrict__ Ah, const unsigned short* __restrict__ Bh,
    unsigned short* __restrict__ Ch, int ldA, int ldB)
{
  const int m0 = by * 128, n0 = bx * 64;
  const int t = threadIdx.x, lane = t & 63;
  const int wid = t >> 6, wr = wid >> 1, wc = wid & 1;

  f32x4 acc[4][2];
  #pragma unroll
  for (int i = 0; i < 4; ++i)
    #pragma unroll
    for (int j = 0; j < 2; ++j)
      acc[i][j] = f32x4{0.f, 0.f, 0.f, 0.f};

  auto stage4k = [&](char* lbuf, const unsigned short* g, int ld, int row0, int k0) {
    int ob = t * 16;
    int e  = ob ^ (((ob >> 7) & 3) << 4);
    int m  = e >> 6, k = (e & 63) >> 1;
    const unsigned short* gp = g + (long)(row0 + m) * ld + k0 + k;
    char* lp = lbuf + (t & ~63) * 16;  // wave-uniform; HW adds lane*16
    __builtin_amdgcn_global_load_lds((gas_t)(const void*)gp, (las_t)(void*)lp, 16, 0, 0);
  };
  // 6 loads per tile: A chunk0 (2), A chunk1 (2), B chunk0 (1), B chunk1 (1)
  auto stageTile = [&](int c, int k0) {
    char* buf = smem + c * 24576;
    stage4k(buf,          Ah, ldA, m0,      k0);
    stage4k(buf + 4096,   Ah, ldA, m0 + 64, k0);
    stage4k(buf + 8192,   Ah, ldA, m0,      k0 + 32);
    stage4k(buf + 12288,  Ah, ldA, m0 + 64, k0 + 32);
    stage4k(buf + 16384,  Bh, ldB, n0,      k0);
    stage4k(buf + 20480,  Bh, ldB, n0,      k0 + 32);
  };
  auto ldfrag = [&](const char* lbuf, int rr) -> f16x8 {
    int ob = rr * 64 + (lane >> 4) * 16;
    ob ^= ((ob >> 7) & 3) << 4;
    return *(const f16x8*)(lbuf + ob);
  };
  auto compute32 = [&](const char* Ac, const char* Bc) {
    f16x8 ah[4];
    #pragma unroll
    for (int mi = 0; mi < 4; ++mi)
      ah[mi] = ldfrag(Ac, wr * 64 + mi * 16 + (lane & 15));
    #pragma unroll
    for (int ni = 0; ni < 2; ++ni) {
      f16x8 bh = ldfrag(Bc, wc * 32 + ni * 16 + (lane & 15));
      #pragma unroll
      for (int mi = 0; mi < 4; ++mi)
        acc[mi][ni] = __builtin_amdgcn_mfma_f32_16x16x32_f16(ah[mi], bh, acc[mi][ni], 0, 0, 0);
    }
  };

  stageTile(0, 0);   // 6 loads in flight
  int cur = 0;
  for (int k0 = 0; k0 < 1024; k0 += 64) {
    if (k0 + 64 < 1024) {
      stageTile(cur ^ 1, k0 + 64);                     // +6 -> 12 in flight
      __builtin_amdgcn_sched_barrier(0);               // pin: loads issued before wait
      asm volatile("s_waitcnt vmcnt(6)" ::: "memory"); // oldest 6 (current tile) done
    } else {
      asm volatile("s_waitcnt vmcnt(0)" ::: "memory");
    }
    __builtin_amdgcn_sched_barrier(0);
    __builtin_amdgcn_s_barrier();      // all waves' current-tile LDS writes landed
    __builtin_amdgcn_sched_barrier(0); // pin: no ds_read hoisted above barrier
    char* buf = smem + cur * 24576;
    compute32(buf, buf + 16384);                // chunk 0
    compute32(buf + 8192, buf + 20480);         // chunk 1
    __builtin_amdgcn_sched_barrier(0); // pin: reads complete before end barrier
    __builtin_amdgcn_s_barrier();      // all waves done reading buf before overwrite
    __builtin_amdgcn_sched_barrier(0); // pin: next iter's loads stay below
    cur ^= 1;
  }

  // epilogue: stage C-tile to LDS fp16, coalesced 16B stores
  unsigned short* ct = (unsigned short*)smem;  // [128][64] (OUT 1) or [64][128] (OUT 3)
  #pragma unroll
  for (int mi = 0; mi < 4; ++mi)
    #pragma unroll
    for (int r = 0; r < 4; ++r) {
      int ml = wr * 64 + mi * 16 + (lane >> 4) * 4 + r;
      #pragma unroll
      for (int ni = 0; ni < 2; ++ni) {
        int nl = wc * 32 + ni * 16 + (lane & 15);
        unsigned short hv = f2h(acc[mi][ni][r]);
        if (OUT == 3) ct[nl * 128 + ml] = hv;
        else          ct[ml * 64 + nl] = hv;
      }
    }
  __syncthreads();

  if (OUT == 1) {
    #pragma unroll
    for (int i = 0; i < 4; ++i) {
      int c = i * 256 + t;
      int ml = c >> 3, cc = (c & 7) * 8;
      int gm = m0 + ml;
      int b = gm >> 6, q = gm & 63;
      long dst = (long)b * 131072 + (long)((n0 >> 10) * 64 + q) * 1024 + (n0 & 1023) + cc;
      *(f16x8*)(Ch + dst) = *(const f16x8*)(ct + ml * 64 + cc);
    }
  } else {  // OUT == 3: P3T[z][h][q]
    #pragma unroll
    for (int i = 0; i < 4; ++i) {
      int c = i * 256 + t;
      int n = c >> 4, rest = c & 15;
      int zi = rest >> 3, cc = (rest & 7) * 8;
      long dst = ((long)((m0 >> 6) + zi) * 1024 + n0 + n) * 64 + cc;
      *(f16x8*)(Ch + dst) = *(const f16x8*)(ct + n * 128 + zi * 64 + cc);
    }
  }
}

// ---------------- generic MFMA GEMM body (R16) for g3-ctx / g4 ----------------
// OUT: 2=fp16 batched, 6=relu+colmax64+final. BF32: B fp32 k-major reg-staged.
template<int BM, int BN, int OUT, bool BF32, int NC>
__device__ __forceinline__ void gemm_body(
    char* smem, int bx, int by, int z,
    const unsigned short* __restrict__ Ah,
    const unsigned short* __restrict__ Bh, const float* __restrict__ Bf,
    float* __restrict__ Cf, unsigned short* __restrict__ Ch,
    int M, int N, int K, int ldA, int ldB, int ldC, long sA, long sB, long sC)
{
  constexpr int ACH = BM * 64, BCH = BN * 64;
  constexpr int MI = BM / 32, NI = BN / 32;
  char* As = smem;
  char* Bs = smem + NC * ACH;

  const int m0 = by * BM, n0 = bx * BN;
  const int t = threadIdx.x, lane = t & 63;
  const int wid = t >> 6, wr = wid >> 1, wc = wid & 1;

  const unsigned short* Ab = Ah + (long)z * sA;
  const unsigned short* Bb = BF32 ? nullptr : Bh + (long)z * sB;
  const float* Bfb = BF32 ? Bf + (long)z * sB : nullptr;

  f32x4 acc[MI][NI];
  #pragma unroll
  for (int i = 0; i < MI; ++i)
    #pragma unroll
    for (int j = 0; j < NI; ++j)
      acc[i][j] = f32x4{0.f, 0.f, 0.f, 0.f};

  auto stage4k = [&](char* lbuf, const unsigned short* g, int ld, int row0, int k0, int rmax) {
    int ob = t * 16;
    int e  = ob ^ (((ob >> 7) & 3) << 4);
    int m  = e >> 6, k = (e & 63) >> 1;
    int row = row0 + m; row = row < rmax ? row : rmax - 1;
    const unsigned short* gp = g + (long)row * ld + k0 + k;
    char* lp = lbuf + (t & ~63) * 16;
    __builtin_amdgcn_global_load_lds((gas_t)(const void*)gp, (las_t)(void*)lp, 16, 0, 0);
  };
  auto stageB_f32 = [&](char* lbuf, const float* g, int ld, int nb, int k0) {
    int ob = t * 16;
    int e  = ob ^ (((ob >> 7) & 3) << 4);
    int n  = e >> 6, kb = (e & 63) >> 1;
    f16x8 pk;
    #pragma unroll
    for (int j = 0; j < 8; ++j) {
      float v = g[(long)(k0 + kb + j) * ld + nb + n];
      pk[j] = (_Float16)v;
    }
    *(f16x8*)(lbuf + ob) = pk;
  };
  auto ldfrag = [&](const char* lbuf, int rr) -> f16x8 {
    int ob = rr * 64 + (lane >> 4) * 16;
    ob ^= ((ob >> 7) & 3) << 4;
    return *(const f16x8*)(lbuf + ob);
  };
  auto compute32 = [&](const char* Ac, const char* Bc) {
    f16x8 ah[MI];
    #pragma unroll
    for (int mi = 0; mi < MI; ++mi)
      ah[mi] = ldfrag(Ac, wr * (BM / 2) + mi * 16 + (lane & 15));
    #pragma unroll
    for (int ni = 0; ni < NI; ++ni) {
      f16x8 bh = ldfrag(Bc, wc * (BN / 2) + ni * 16 + (lane & 15));
      #pragma unroll
      for (int mi = 0; mi < MI; ++mi)
        acc[mi][ni] = __builtin_amdgcn_mfma_f32_16x16x32_f16(ah[mi], bh, acc[mi][ni], 0, 0, 0);
    }
  };

  for (int k0 = 0; k0 < K; k0 += 32 * NC) {
    #pragma unroll
    for (int c = 0; c < NC; ++c) {
      stage4k(As + c * ACH, Ab, ldA, m0, k0 + 32 * c, M);
      if (BM == 128) stage4k(As + c * ACH + 4096, Ab, ldA, m0 + 64, k0 + 32 * c, M);
    }
    #pragma unroll
    for (int c = 0; c < NC; ++c) {
      if (BF32) stageB_f32(Bs + c * BCH, Bfb, ldB, n0, k0 + 32 * c);
      else      stage4k(Bs + c * BCH, Bb, ldB, n0, k0 + 32 * c, N);
    }
    __syncthreads();
    #pragma unroll
    for (int c = 0; c < NC; ++c) compute32(As + c * ACH, Bs + c * BCH);
    __syncthreads();
  }

  if (OUT == 6) {
    float* red = (float*)smem;
    #pragma unroll
    for (int ni = 0; ni < NI; ++ni) {
      float pm = 0.0f;  // relu floor
      #pragma unroll
      for (int mi = 0; mi < MI; ++mi)
        #pragma unroll
        for (int r = 0; r < 4; ++r)
          pm = fmaxf(pm, acc[mi][ni][r]);
      int g = wr * 4 + (lane >> 4);
      int col = wc * (BN / 2) + ni * 16 + (lane & 15);
      red[g * BN + col] = pm;
    }
    __syncthreads();
    if (t < BN) {
      float pq = red[t];
      #pragma unroll
      for (int g = 1; g < 8; ++g) pq = fmaxf(pq, red[g * BN + t]);
      float pa = Bf[(long)(by * 4) * 1024 + n0 + t];
      #pragma unroll
      for (int mt = 1; mt < 4; ++mt)
        pa = fmaxf(pa, Bf[(long)(by * 4 + mt) * 1024 + n0 + t]);
      Cf[(long)by * 1024 + n0 + t] = 0.5f * pa + 0.5f * pq;
    }
    return;
  }

  // OUT == 2: coalesced LDS-gathered stores
  unsigned short* ct = (unsigned short*)smem;
  #pragma unroll
  for (int mi = 0; mi < MI; ++mi)
    #pragma unroll
    for (int r = 0; r < 4; ++r) {
      int ml = wr * (BM / 2) + mi * 16 + (lane >> 4) * 4 + r;
      #pragma unroll
      for (int ni = 0; ni < NI; ++ni) {
        int nl = wc * (BN / 2) + ni * 16 + (lane & 15);
        ct[ml * BN + nl] = f2h(acc[mi][ni][r]);
      }
    }
  __syncthreads();
  constexpr int ITER = BM * (BN / 8) / 256;
  #pragma unroll
  for (int i = 0; i < ITER; ++i) {
    int c = i * 256 + t;
    int ml = c / (BN / 8), cc = (c % (BN / 8)) * 8;
    long dst = (long)z * sC + (long)(m0 + ml) * ldC + n0 + cc;
    *(f16x8*)(Ch + dst) = *(const f16x8*)(ct + ml * BN + cc);
  }
}

// ---------------- g1: Pcat (128x64) || P3T (128x64), 768 blocks, pipelined ----------------

__global__ __launch_bounds__(256) void g1_kernel(
    const unsigned short* Q_hi, const unsigned short* Wcat, const unsigned short* W21T,
    unsigned short* Pcat, unsigned short* P3T)
{
  __shared__ char smem[49152];
  int bid = blockIdx.x;  // natural order: round-robin across XCDs
  if (bid < 512) {   // Pcat: M=2048,N=2048,K=1024
    gemm_pipe<1>(smem, bid & 31, bid >> 5, Q_hi, Wcat, Pcat, 1024, 1024);
  } else {           // P3T: M=2048,N=1024,K=1024
    int b2 = bid - 512;
    gemm_pipe<3>(smem, b2 & 15, b2 >> 4, Q_hi, W21T, P3T, 1024, 1024);
  }
}

// ---------------- g2: scores, 32x128 full-K, BK=128, fused aq softmax ----------------

__global__ __launch_bounds__(512) void g2_kernel(
    const float* __restrict__ Afeat, const unsigned short* __restrict__ Pcat,
    unsigned short* __restrict__ aq, float* __restrict__ Spar)
{
  __shared__ char smem[40960];   // A: 4 x 2KB, B: 4 x 8KB
  auto Ac = [&](int c) { return smem + c * 2048; };
  auto Bc = [&](int c) { return smem + 8192 + c * 8192; };

  int orig = blockIdx.x;            // 512 blocks; z-grouped for Pcat L2 residence
  int xcd = orig & 7, idx = orig >> 3;
  int z   = xcd * 4 + (idx >> 4);
  int mt  = idx & 15;
  const int m0 = mt * 32;
  const int t = threadIdx.x, lane = t & 63;
  const int wid = t >> 6, wr = wid >> 2, wc = wid & 3;  // 2 x 4 waves

  const float* Ab = Afeat + (long)z * 524288;
  const unsigned short* Bb = Pcat + (long)z * 131072;

  f32x4 acc[2];
  acc[0] = f32x4{0.f, 0.f, 0.f, 0.f};
  acc[1] = f32x4{0.f, 0.f, 0.f, 0.f};

  auto ldfrag = [&](const char* lbuf, int rr) -> f16x8 {
    int ob = rr * 64 + (lane >> 4) * 16;
    ob ^= ((ob >> 7) & 3) << 4;
    return *(const f16x8*)(lbuf + ob);
  };
  auto stageA2 = [&](int c0k, int k0) {
    int half = t >> 8, tt = t & 255;
    int ob = tt * 8;
    int e  = ob ^ (((ob >> 7) & 3) << 4);
    int m  = e >> 6, ke = (e & 63) >> 1;
    float4 v = *(const float4*)(Ab + (long)(m0 + m) * 1024 + k0 + half * 32 + ke);
    ushort4 h;
    h.x = f2h(v.x); h.y = f2h(v.y); h.z = f2h(v.z); h.w = f2h(v.w);
    *(ushort4*)(Ac(c0k + half) + ob) = h;
  };
  auto stageB = [&](int c, int k0) {
    int ob = t * 16;
    int e  = ob ^ (((ob >> 7) & 3) << 4);
    int n  = e >> 6, kk = (e & 63) >> 1;
    const unsigned short* gp = Bb + (long)n * 1024 + k0 + kk;
    char* lp = Bc(c) + (t & ~63) * 16;
    __builtin_amdgcn_global_load_lds((gas_t)(const void*)gp, (las_t)(void*)lp, 16, 0, 0);
  };
  auto compute32 = [&](const char* Aq, const char* Bq) {
    f16x8 ah = ldfrag(Aq, wr * 16 + (lane & 15));
    #pragma unroll
    for (int ni = 0; ni < 2; ++ni) {
      f16x8 bh = ldfrag(Bq, wc * 32 + ni * 16 + (lane & 15));
      acc[ni] = __builtin_amdgcn_mfma_f32_16x16x32_f16(ah, bh, acc[ni], 0, 0, 0);
    }
  };

  for (int k0 = 0; k0 < 1024; k0 += 128) {
    stageA2(0, k0);
    stageA2(2, k0 + 64);
    #pragma unroll
    for (int c = 0; c < 4; ++c) stageB(c, k0 + 32 * c);
    __syncthreads();
    #pragma unroll
    for (int c = 0; c < 4; ++c) compute32(Ac(c), Bc(c));
    __syncthreads();
  }

  float* red = (float*)smem;  // [32][128] = 16KB
  #pragma unroll
  for (int ni = 0; ni < 2; ++ni)
    #pragma unroll
    for (int r = 0; r < 4; ++r) {
      int lrow = wr * 16 + (lane >> 4) * 4 + r;
      int col  = wc * 32 + ni * 16 + (lane & 15);
      red[lrow * 128 + col] = acc[ni][r];
    }
  __syncthreads();

  int row = t >> 4, cg = (t & 15) * 4;
  float a0 = red[row * 128 + cg],     a1 = red[row * 128 + cg + 1];
  float a2 = red[row * 128 + cg + 2], a3 = red[row * 128 + cg + 3];
  float4 vq = *(float4*)&red[row * 128 + 64 + cg];
  float mx = fmaxf(fmaxf(a0, a1), fmaxf(a2, a3));
  #pragma unroll
  for (int off = 8; off; off >>= 1) mx = fmaxf(mx, __shfl_xor(mx, off));
  float e0 = __expf(a0 - mx), e1 = __expf(a1 - mx);
  float e2 = __expf(a2 - mx), e3 = __expf(a3 - mx);
  float s = (e0 + e1) + (e2 + e3);
  #pragma unroll
  for (int off = 8; off; off >>= 1) s += __shfl_xor(s, off);
  float inv = 1.0f / s;
  ushort4 h;
  h.x = f2h(e0 * inv); h.y = f2h(e1 * inv); h.z = f2h(e2 * inv); h.w = f2h(e3 * inv);
  long base = (long)z * 32768 + (long)(m0 + row) * 64 + cg;
  *(ushort4*)(aq + base) = h;
  *(float4*)(Spar + base) = vq;
}

// ---------------- qa col-softmax ----------------

__global__ __launch_bounds__(256) void softmax_cols(const float* __restrict__ Sp,
                                                    unsigned short* __restrict__ qa)
{
  int bq = blockIdx.x;
  int b = bq >> 6, q = bq & 63;
  int t = threadIdx.x;
  const float* base = Sp + (long)b * 32768 + q;
  float v0 = base[(long)t * 64];
  float v1 = base[(long)(t + 256) * 64];
  float m = fmaxf(v0, v1);
  #pragma unroll
  for (int off = 32; off; off >>= 1) m = fmaxf(m, __shfl_xor(m, off));
  __shared__ float sm[4], ss[4];
  int wid = t >> 6, lane = t & 63;
  if (lane == 0) sm[wid] = m;
  __syncthreads();
  float M = fmaxf(fmaxf(sm[0], sm[1]), fmaxf(sm[2], sm[3]));
  float e0 = __expf(v0 - M), e1 = __expf(v1 - M);
  float s = e0 + e1;
  #pragma unroll
  for (int off = 32; off; off >>= 1) s += __shfl_xor(s, off);
  if (lane == 0) ss[wid] = s;
  __syncthreads();
  float inv = 1.0f / ((ss[0] + ss[1]) + (ss[2] + ss[3]));
  qa[(long)bq * 512 + t]       = f2h(e0 * inv);
  qa[(long)bq * 512 + t + 256] = f2h(e1 * inv);
}

// ---------------- g3: PmaxA (LDS-free, K=64) || ctx (BK=64), natural order ----------------

__global__ __launch_bounds__(256) void g3_kernel(
    const unsigned short* aq, const unsigned short* P3T, float* PmaxA,
    const unsigned short* qa, const float* Afeat, unsigned short* ctx)
{
  __shared__ char smem[16384];
  int bid = blockIdx.x;
  if (bid < 1024) {
    int bx = bid & 7, by = (bid >> 3) & 3, z = bid >> 5;
    int n0 = bx * 128, m0 = by * 128;
    const unsigned short* Aq = aq + (long)z * 32768;
    const unsigned short* Bp = P3T + (long)z * 65536;
    const int t = threadIdx.x, lane = t & 63;
    const int wid = t >> 6, wr = wid >> 1, wc = wid & 1;

    f32x4 acc[4][4];
    #pragma unroll
    for (int i = 0; i < 4; ++i)
      #pragma unroll
      for (int j = 0; j < 4; ++j)
        acc[i][j] = f32x4{0.f, 0.f, 0.f, 0.f};

    #pragma unroll
    for (int c = 0; c < 2; ++c) {
      f16x8 ah[4];
      #pragma unroll
      for (int mi = 0; mi < 4; ++mi) {
        int row = m0 + wr * 64 + mi * 16 + (lane & 15);
        ah[mi] = *(const f16x8*)(Aq + (long)row * 64 + c * 32 + (lane >> 4) * 8);
      }
      #pragma unroll
      for (int ni = 0; ni < 4; ++ni) {
        int rc = n0 + wc * 64 + ni * 16 + (lane & 15);
        f16x8 bh = *(const f16x8*)(Bp + (long)rc * 64 + c * 32 + (lane >> 4) * 8);
        #pragma unroll
        for (int mi = 0; mi < 4; ++mi)
          acc[mi][ni] = __builtin_amdgcn_mfma_f32_16x16x32_f16(ah[mi], bh, acc[mi][ni], 0, 0, 0);
      }
    }

    float* red = (float*)smem;
    #pragma unroll
    for (int ni = 0; ni < 4; ++ni) {
      float pm = 0.0f;  // relu floor
      #pragma unroll
      for (int mi = 0; mi < 4; ++mi)
        #pragma unroll
        for (int r = 0; r < 4; ++r)
          pm = fmaxf(pm, acc[mi][ni][r]);
      int g = wr * 4 + (lane >> 4);
      int col = wc * 64 + ni * 16 + (lane & 15);
      red[g * 128 + col] = pm;
    }
    __syncthreads();
    if (t < 128) {
      float m = red[t];
      #pragma unroll
      for (int g = 1; g < 8; ++g) m = fmaxf(m, red[g * 128 + t]);
      PmaxA[(long)(z * 4 + by) * 1024 + n0 + t] = m;
    }
  } else {
    int b2 = bid - 1024;
    gemm_body<64, 64, 2, true, 2>(smem, b2 & 15, 0, b2 >> 4,
        qa, nullptr, Afeat, nullptr, ctx,
        64, 1024, 512, 512, 1024, 1024, 32768L, 524288L, 65536L);
  }
}

// ---------------- g4: PmaxQ colmax + fused final combine, BK=128 ----------------

__global__ __launch_bounds__(256) void g4_kernel(
    const unsigned short* ctx, const unsigned short* W22T,
    const float* PmaxA, float* out)
{
  __shared__ char smem[32768];
  gemm_body<64, 64, 6, false, 4>(smem, blockIdx.x, blockIdx.y, 0,
      ctx, W22T, PmaxA, out, nullptr,
      2048, 1024, 1024, 1024, 1024, 1024, 0, 0, 0);
}

// ---------------- launch ----------------

extern "C" void kernel_launch(void* const* d_in, const int* in_sizes, int n_in,
                              void* d_out, int out_size, void* d_ws, size_t ws_size,
                              hipStream_t stream) {
  const float* Afeat = (const float*)d_in[0];
  const float* Qfeat = (const float*)d_in[1];
  const float* W11   = (const float*)d_in[2];
  const float* W12   = (const float*)d_in[3];
  const float* W21   = (const float*)d_in[4];
  const float* W22   = (const float*)d_in[5];
  float* out = (float*)d_out;

  char* w = (char*)d_ws;
  auto alloc = [&](long bytes) { char* p = w; w += bytes; return p; };
  unsigned short* Q_hi  = (unsigned short*)alloc(4194304);
  unsigned short* Wcat  = (unsigned short*)alloc(4194304);   // [2048][1024] fp16: W11 ; W12^T
  unsigned short* W21T  = (unsigned short*)alloc(2097152);
  unsigned short* W22T  = (unsigned short*)alloc(2097152);
  unsigned short* Pcat  = (unsigned short*)alloc(8388608);   // [32][128][1024]
  unsigned short* P3T   = (unsigned short*)alloc(4194304);   // [32][1024][64]
  float*          Spar  = (float*)alloc(4194304);            // [32][512][64] qa scores
  unsigned short* aq    = (unsigned short*)alloc(2097152);   // [32][512][64]
  unsigned short* qa    = (unsigned short*)alloc(2097152);   // [32][64][512]
  unsigned short* ctx   = (unsigned short*)alloc(4194304);   // [32][64][1024]
  float*          PmaxA = (float*)alloc(524288);             // [128][1024]

  dim3 blk(256), tblk(32, 8);

  prep_all<<<dim3(32, 32, 6), tblk, 0, stream>>>(W11, W12, W21, W22, Qfeat,
                                                 Wcat, W21T, W22T, Q_hi);
  g1_kernel<<<768, blk, 0, stream>>>(Q_hi, Wcat, W21T, Pcat, P3T);
  g2_kernel<<<512, dim3(512), 0, stream>>>(Afeat, Pcat, aq, Spar);
  softmax_cols<<<2048, blk, 0, stream>>>(Spar, qa);
  g3_kernel<<<1536, blk, 0, stream>>>(aq, P3T, PmaxA, qa, Afeat, ctx);
  g4_kernel<<<dim3(16, 32), blk, 0, stream>>>(ctx, W22T, PmaxA, out);
}